// Round 17
// baseline (2263.347 us; speedup 1.0000x reference)
//
#include <hip/hip_runtime.h>

#define N_NODES 20000
#define N_EDGES 320000
#define ETOT (N_EDGES + N_NODES)
#define G_GROUPS 64
#define BN_BANKS 8

typedef __attribute__((ext_vector_type(8))) short bf16x8;
typedef __attribute__((ext_vector_type(4))) float f32x4;

// bf16 helpers (RNE)
__device__ __forceinline__ unsigned short f2bf(float f) {
    unsigned int u = __float_as_uint(f);
    u += 0x7fffu + ((u >> 16) & 1u);
    return (unsigned short)(u >> 16);
}
__device__ __forceinline__ float bf2f(unsigned short v) {
    return __uint_as_float(((unsigned int)v) << 16);
}
__device__ __forceinline__ unsigned int pack2bf(float a, float b) {
    return (unsigned int)f2bf(a) | ((unsigned int)f2bf(b) << 16);
}

// ---------------- CSR build ----------------

__global__ __launch_bounds__(256) void k_hist(const int* __restrict__ ei, int* __restrict__ counts) {
    int e = blockIdx.x * 256 + threadIdx.x;
    if (e >= ETOT) return;
    int dst = (e < N_EDGES) ? ei[N_EDGES + e] : (e - N_EDGES);
    atomicAdd(&counts[dst], 1);
}

__global__ __launch_bounds__(1024) void k_scan(const int* __restrict__ counts, int* __restrict__ offs,
                                               int* __restrict__ cursor) {
    __shared__ int sdata[1024];
    const int t = threadIdx.x;
    const int chunk = (N_NODES + 1023) / 1024;  // 20
    int base = t * chunk;
    int s = 0;
    for (int i = 0; i < chunk; i++) { int idx = base + i; if (idx < N_NODES) s += counts[idx]; }
    sdata[t] = s;
    __syncthreads();
    for (int off = 1; off < 1024; off <<= 1) {
        int v = (t >= off) ? sdata[t - off] : 0;
        __syncthreads();
        sdata[t] += v;
        __syncthreads();
    }
    int prefix = (t == 0) ? 0 : sdata[t - 1];
    for (int i = 0; i < chunk; i++) {
        int idx = base + i;
        if (idx < N_NODES) {
            int cv = counts[idx];
            offs[idx] = prefix;
            cursor[idx] = prefix;
            prefix += cv;
        }
    }
    if (t == 1023) offs[N_NODES] = sdata[1023];
}

__global__ __launch_bounds__(256) void k_scatter(const int* __restrict__ ei, int* __restrict__ cursor,
                                                 int* __restrict__ csr_src) {
    int e = blockIdx.x * 256 + threadIdx.x;
    if (e >= ETOT) return;
    int src = (e < N_EDGES) ? ei[e] : (e - N_EDGES);
    int dst = (e < N_EDGES) ? ei[N_EDGES + e] : (e - N_EDGES);
    int p = atomicAdd(&cursor[dst], 1);
    csr_src[p] = src;
}

// ---------------- pre-pack all weights -> B-fragment-major bf16, ONE dispatch ----------------

__global__ __launch_bounds__(256) void k_prepB_all(const float* __restrict__ W2a, const float* __restrict__ W2b,
                                                   const float* __restrict__ W1a, const float* __restrict__ Wra,
                                                   const float* __restrict__ W1b, const float* __restrict__ Wrb,
                                                   unsigned short* __restrict__ B2a, unsigned short* __restrict__ B2b,
                                                   unsigned short* __restrict__ B1a, unsigned short* __restrict__ Bra,
                                                   unsigned short* __restrict__ B1b, unsigned short* __restrict__ Brb) {
    int b = blockIdx.x;
    const float* W;
    unsigned short* Bf;
    int s0;
    if (b < 32) { W = W2a; Bf = B2a; s0 = b; }
    else if (b < 64) { W = W2b; Bf = B2b; s0 = b - 32; }
    else if (b < 72) { W = W1a; Bf = B1a; s0 = b - 64; }
    else if (b < 80) { W = Wra; Bf = Bra; s0 = b - 72; }
    else if (b < 88) { W = W1b; Bf = B1b; s0 = b - 80; }
    else { W = Wrb; Bf = Brb; s0 = b - 88; }
    int s = s0 * 256 + threadIdx.x;
    int l = s & 63;
    int nt = (s >> 6) & 15;
    int kt = s >> 10;
    int n = nt * 16 + (l & 15);
    int kb = kt * 32 + (l >> 4) * 8;
    float v[8];
    #pragma unroll
    for (int j = 0; j < 8; j++) v[j] = W[(kb + j) * 256 + n];
    uint4 q = {pack2bf(v[0], v[1]), pack2bf(v[2], v[3]), pack2bf(v[4], v[5]), pack2bf(v[6], v[7])};
    *(uint4*)(Bf + s * 8) = q;
}

// ---------------- MFMA dual GEMM [N,64]x[64,256] (W1 & Wr), alpha fused ----------------

__global__ __launch_bounds__(256) void k_gemm64_dual(const float* __restrict__ x,
                                                     const unsigned short* __restrict__ Bf1,
                                                     const unsigned short* __restrict__ Bfr,
                                                     const float* __restrict__ br,
                                                     const float* __restrict__ a_s, const float* __restrict__ a_d,
                                                     unsigned short* __restrict__ hbf, float* __restrict__ res,
                                                     float* __restrict__ alS, float* __restrict__ alD) {
    const int rb = blockIdx.x >> 2, cs = blockIdx.x & 3;
    const int row0 = rb * 64;
    const int nrows = min(64, N_NODES - row0);
    const int t = threadIdx.x;
    const int w = t >> 6;
    const int l = t & 63;
    const int quad = l >> 4;
    const int colLocal = l & 15;
    __shared__ unsigned short As[8 * 64 * 8];  // 8 KB
    __shared__ float alsm[4][64], aldm[4][64];

    const int ntg = cs * 4 + w;
    bf16x8 b1f[2], brf[2];
    #pragma unroll
    for (int kt = 0; kt < 2; kt++) {
        b1f[kt] = *(const bf16x8*)(Bf1 + ((kt * 16 + ntg) * 64 + l) * 8);
        brf[kt] = *(const bf16x8*)(Bfr + ((kt * 16 + ntg) * 64 + l) * 8);
    }

    #pragma unroll
    for (int gi = 0; gi < 2; gi++) {
        int g = 2 * w + gi;
        int kt = g >> 2, mt = g & 3;
        int sm = mt * 16 + (l & 15);
        int koff = kt * 32 + (l >> 4) * 8;
        float4 v0 = {0.f, 0.f, 0.f, 0.f}, v1 = {0.f, 0.f, 0.f, 0.f};
        if (sm < nrows) {
            v0 = *(const float4*)(x + (row0 + sm) * 64 + koff);
            v1 = *(const float4*)(x + (row0 + sm) * 64 + koff + 4);
        }
        uint4 q = {pack2bf(v0.x, v0.y), pack2bf(v0.z, v0.w), pack2bf(v1.x, v1.y), pack2bf(v1.z, v1.w)};
        *(uint4*)(As + (g * 64 + l) * 8) = q;
    }
    __syncthreads();

    f32x4 acc1[4], acc2[4];
    #pragma unroll
    for (int mt = 0; mt < 4; mt++) {
        acc1[mt] = (f32x4){0.f, 0.f, 0.f, 0.f};
        acc2[mt] = (f32x4){0.f, 0.f, 0.f, 0.f};
    }
    #pragma unroll
    for (int kt = 0; kt < 2; kt++) {
        #pragma unroll
        for (int mt = 0; mt < 4; mt++) {
            bf16x8 af = *(const bf16x8*)(As + ((kt * 4 + mt) * 64 + l) * 8);
            acc1[mt] = __builtin_amdgcn_mfma_f32_16x16x32_bf16(af, b1f[kt], acc1[mt], 0, 0, 0);
            acc2[mt] = __builtin_amdgcn_mfma_f32_16x16x32_bf16(af, brf[kt], acc2[mt], 0, 0, 0);
        }
    }

    const int col = cs * 64 + w * 16 + colLocal;
    const float brv = br[col];
    const float asv = a_s[col];
    const float adv = a_d[col];
    #pragma unroll
    for (int mt = 0; mt < 4; mt++) {
        #pragma unroll
        for (int r = 0; r < 4; r++) {
            float v1 = acc1[mt][r];
            int lr = mt * 16 + quad * 4 + r;
            bool ok = lr < nrows;
            int row = row0 + lr;
            if (ok) {
                hbf[row * 256 + col] = f2bf(v1);
                res[row * 256 + col] = acc2[mt][r] + brv;
            }
            float ps = v1 * asv, pd = v1 * adv;
            #pragma unroll
            for (int off = 1; off < 16; off <<= 1) {
                ps += __shfl_xor(ps, off);
                pd += __shfl_xor(pd, off);
            }
            if (colLocal == 0) {
                alsm[w][lr] = ps;
                aldm[w][lr] = pd;
            }
        }
    }
    __syncthreads();
    if (t < 64 && t < nrows) {
        float s = (alsm[0][t] + alsm[1][t]) + (alsm[2][t] + alsm[3][t]);
        float d = (aldm[0][t] + aldm[1][t]) + (aldm[2][t] + aldm[3][t]);
        alS[(row0 + t) * 4 + cs] = s;
        alD[(row0 + t) * 4 + cs] = d;
    }
}

// ---------------- fused CSR softmax-aggregation + BatchNorm stats/finalize ----------------
// agg as before (scalar index/logit loads, 16-deep gathers). BN: per-block column sums of the
// 4 output rows via per-wave LDS stores + cross-wave reduce, banked global atomics
// (5000/8 = 625 adds/address), hierarchical last-block-done (per-bank counters 64B apart ->
// master), finalize computes scale/shift and re-zeroes accumulators+counters.

template <int H>
__global__ __launch_bounds__(256) void k_agg_bn(const unsigned short* __restrict__ hbf,
                                               const float* __restrict__ alS, const float* __restrict__ alD,
                                               const int* __restrict__ offs, const int* __restrict__ csr_src,
                                               const float* __restrict__ bias, float* __restrict__ out,
                                               float* __restrict__ sumR, float* __restrict__ sumsqR,
                                               const float* __restrict__ g, const float* __restrict__ be,
                                               float* __restrict__ scale, float* __restrict__ shift,
                                               int* __restrict__ cntBank, int* __restrict__ cntMaster,
                                               float* __restrict__ zS, float* __restrict__ zD) {
    const int node = __builtin_amdgcn_readfirstlane(blockIdx.x * 4 + (threadIdx.x >> 6));  // grid exact 5000*4
    const int t = threadIdx.x;
    const int lane = t & 63;
    const int w = t >> 6;
    const int head = (H == 4) ? (lane >> 4) : 0;
    __shared__ float lsum[4][256], lqsum[4][256];

    if (H == 4 && lane == 0) { zS[node] = 0.f; zD[node] = 0.f; }  // zero next-phase alpha accum

    float ald;
    if (H == 4) {
        float4 d4 = *(const float4*)(alD + node * 4);
        ald = (head == 0) ? d4.x : (head == 1) ? d4.y : (head == 2) ? d4.z : d4.w;
    } else {
        ald = alD[node];
    }
    const int e0 = offs[node], e1 = offs[node + 1];
    const unsigned short* hp = hbf + lane * 4;
    float den = 0.f, a0 = 0.f, a1 = 0.f, a2 = 0.f, a3 = 0.f;
    int e = e0;
    for (; e + 16 <= e1; e += 16) {
        int s[16];
        #pragma unroll
        for (int i = 0; i < 16; i++) s[i] = csr_src[e + i];
        ushort4 hq[16];
        #pragma unroll
        for (int i = 0; i < 16; i++) hq[i] = *(const ushort4*)(hp + s[i] * 256);
        float wq[16];
        #pragma unroll
        for (int i = 0; i < 16; i++) {
            float v;
            if (H == 4) {
                float4 s4 = *(const float4*)(alS + s[i] * 4);
                float as = (head == 0) ? s4.x : (head == 1) ? s4.y : (head == 2) ? s4.z : s4.w;
                v = as + ald;
            } else {
                v = alS[s[i]] + ald;
            }
            v = (v > 0.f) ? v : 0.2f * v;
            wq[i] = __expf(v);
        }
        #pragma unroll
        for (int i = 0; i < 16; i++) {
            den += wq[i];
            a0 += wq[i] * bf2f(hq[i].x); a1 += wq[i] * bf2f(hq[i].y);
            a2 += wq[i] * bf2f(hq[i].z); a3 += wq[i] * bf2f(hq[i].w);
        }
    }
    for (; e < e1; e++) {
        int s = csr_src[e];
        float v;
        if (H == 4) {
            float4 s4 = *(const float4*)(alS + s * 4);
            float as = (head == 0) ? s4.x : (head == 1) ? s4.y : (head == 2) ? s4.z : s4.w;
            v = as + ald;
        } else {
            v = alS[s] + ald;
        }
        v = (v > 0.f) ? v : 0.2f * v;
        float wv = __expf(v);
        ushort4 hq = *(const ushort4*)(hp + s * 256);
        den += wv;
        a0 += wv * bf2f(hq.x); a1 += wv * bf2f(hq.y); a2 += wv * bf2f(hq.z); a3 += wv * bf2f(hq.w);
    }
    float inv = 1.f / den;
    const float4 bv = *(const float4*)(bias + lane * 4);
    float4 o = {a0 * inv + bv.x, a1 * inv + bv.y, a2 * inv + bv.z, a3 * inv + bv.w};
    *(float4*)(out + node * 256 + lane * 4) = o;

    // ---- BN partials: this wave's row at cols [lane*4, +4) ----
    *(float4*)(&lsum[w][lane * 4]) = o;
    float4 q2 = {o.x * o.x, o.y * o.y, o.z * o.z, o.w * o.w};
    *(float4*)(&lqsum[w][lane * 4]) = q2;
    __syncthreads();
    const int bank = blockIdx.x & (BN_BANKS - 1);
    {
        float s4 = (lsum[0][t] + lsum[1][t]) + (lsum[2][t] + lsum[3][t]);
        float q4 = (lqsum[0][t] + lqsum[1][t]) + (lqsum[2][t] + lqsum[3][t]);
        atomicAdd(&sumR[bank * 256 + t], s4);
        atomicAdd(&sumsqR[bank * 256 + t], q4);
    }
    __threadfence();
    __syncthreads();
    __shared__ int lastFlag;
    if (t == 0) {
        int done = atomicAdd(&cntBank[bank * 16], 1);               // counters 64B apart
        int lastInBank = (done == (int)(gridDim.x / BN_BANKS) - 1);  // 5000/8 = 625 exact
        int m = 0;
        if (lastInBank) m = atomicAdd(cntMaster, 1);
        lastFlag = (lastInBank && m == BN_BANKS - 1);
    }
    __syncthreads();
    if (lastFlag) {
        const int c = t;
        float S = 0.f, Q = 0.f;
        #pragma unroll
        for (int k = 0; k < BN_BANKS; k++) {
            S += atomicAdd(&sumR[k * 256 + c], 0.f);  // coherent read
            Q += atomicAdd(&sumsqR[k * 256 + c], 0.f);
        }
        float mu = S * (1.f / N_NODES);
        float var = Q * (1.f / N_NODES) - mu * mu;
        float sc = g[c] * rsqrtf(var + 1e-5f);
        scale[c] = sc;
        shift[c] = be[c] - mu * sc;
        #pragma unroll
        for (int k = 0; k < BN_BANKS; k++) {  // re-zero for next BN use
            sumR[k * 256 + c] = 0.f;
            sumsqR[k * 256 + c] = 0.f;
        }
        if (c < BN_BANKS) cntBank[c * 16] = 0;
        if (c == 0) *cntMaster = 0;
    }
}

// ---------------- MFMA GEMM: bf16(relu(bn(A))) @ bf16(W2), alpha via atomics ----------------

__global__ __launch_bounds__(256) void k_gemm256_mfma(const float* __restrict__ A, const float* __restrict__ scale,
                                                      const float* __restrict__ shift,
                                                      const unsigned short* __restrict__ Bf,
                                                      const float* __restrict__ a_s, const float* __restrict__ a_d,
                                                      unsigned short* __restrict__ C, float* __restrict__ alS2,
                                                      float* __restrict__ alD2) {
    const int rb = blockIdx.x >> 2, cs = blockIdx.x & 3;
    const int row0 = rb * 64;
    const int nrows = min(64, N_NODES - row0);
    const int t = threadIdx.x;
    const int w = t >> 6;
    const int l = t & 63;
    const int quad = l >> 4;
    const int colLocal = l & 15;
    __shared__ unsigned short As[2 * 4 * 64 * 8];  // 8 KB
    __shared__ float scs[256], shs[256];
    scs[t] = scale[t];
    shs[t] = shift[t];

    const int ntg = cs * 4 + w;
    bf16x8 bfrag[8];
    #pragma unroll
    for (int kt = 0; kt < 8; kt++)
        bfrag[kt] = *(const bf16x8*)(Bf + ((kt * 16 + ntg) * 64 + l) * 8);

    f32x4 acc[4];
    #pragma unroll
    for (int mt = 0; mt < 4; mt++) acc[mt] = (f32x4){0.f, 0.f, 0.f, 0.f};

    const int smt = (t >> 6) & 3;
    const int sm = smt * 16 + (l & 15);
    const int skoff = (l >> 4) * 8;

    for (int kc = 0; kc < 4; kc++) {
        __syncthreads();
        #pragma unroll
        for (int kt2 = 0; kt2 < 2; kt2++) {
            int k = kc * 64 + kt2 * 32 + skoff;
            float4 v0 = {0.f, 0.f, 0.f, 0.f}, v1 = {0.f, 0.f, 0.f, 0.f};
            if (sm < nrows) {
                v0 = *(const float4*)(A + (row0 + sm) * 256 + k);
                v1 = *(const float4*)(A + (row0 + sm) * 256 + k + 4);
                v0.x = fmaxf(v0.x * scs[k + 0] + shs[k + 0], 0.f);
                v0.y = fmaxf(v0.y * scs[k + 1] + shs[k + 1], 0.f);
                v0.z = fmaxf(v0.z * scs[k + 2] + shs[k + 2], 0.f);
                v0.w = fmaxf(v0.w * scs[k + 3] + shs[k + 3], 0.f);
                v1.x = fmaxf(v1.x * scs[k + 4] + shs[k + 4], 0.f);
                v1.y = fmaxf(v1.y * scs[k + 5] + shs[k + 5], 0.f);
                v1.z = fmaxf(v1.z * scs[k + 6] + shs[k + 6], 0.f);
                v1.w = fmaxf(v1.w * scs[k + 7] + shs[k + 7], 0.f);
            }
            uint4 q = {pack2bf(v0.x, v0.y), pack2bf(v0.z, v0.w), pack2bf(v1.x, v1.y), pack2bf(v1.z, v1.w)};
            *(uint4*)(As + ((kt2 * 4 + smt) * 64 + l) * 8) = q;
        }
        __syncthreads();
        #pragma unroll
        for (int kt2 = 0; kt2 < 2; kt2++) {
            int ktg = kc * 2 + kt2;
            #pragma unroll
            for (int mt = 0; mt < 4; mt++) {
                bf16x8 af = *(const bf16x8*)(As + ((kt2 * 4 + mt) * 64 + l) * 8);
                acc[mt] = __builtin_amdgcn_mfma_f32_16x16x32_bf16(af, bfrag[ktg], acc[mt], 0, 0, 0);
            }
        }
    }

    const int col = cs * 64 + w * 16 + colLocal;
    const float asv = a_s[col];
    const float adv = a_d[col];
    #pragma unroll
    for (int mt = 0; mt < 4; mt++) {
        #pragma unroll
        for (int r = 0; r < 4; r++) {
            float v = acc[mt][r];
            int lr = mt * 16 + quad * 4 + r;
            bool ok = lr < nrows;
            int row = row0 + lr;
            if (ok) C[row * 256 + col] = f2bf(v);
            float ps = v * asv, pd = v * adv;
            #pragma unroll
            for (int off = 1; off < 16; off <<= 1) {
                ps += __shfl_xor(ps, off);
                pd += __shfl_xor(pd, off);
            }
            if (colLocal == 0 && ok) {
                atomicAdd(&alS2[row], ps);
                atomicAdd(&alD2[row], pd);
            }
        }
    }
}

// ---------------- final GEMM ((relu(bn(A))+res)*invsqrt2)@Wf+bf -> [N,64], 32x64 tiles ----------------

__global__ __launch_bounds__(256) void k_gemm_final(const float* __restrict__ A, const float* __restrict__ scale,
                                                    const float* __restrict__ shift, const float* __restrict__ res,
                                                    const float* __restrict__ B, const float* __restrict__ bias,
                                                    float* __restrict__ y) {
    const int row0 = blockIdx.x * 32;
    const int t = threadIdx.x;
    const float INVS = 0.70710678118654752440f;
    __shared__ float xs[32 * 36];
    __shared__ float bs[32 * 64];
    __shared__ float scs[256], shs[256];
    scs[t] = scale[t];
    shs[t] = shift[t];
    const int rf = (t & 15) | ((t >> 7) << 4);
    const int cf = (t >> 4) & 7;
    const int c0 = (t & 15) * 4;
    const int r0 = (t >> 4) * 2;
    float acc[2][4] = {};
    for (int k0 = 0; k0 < 256; k0 += 32) {
        __syncthreads();
        {
            int kcol = k0 + cf * 4;
            int gi = (row0 + rf) * 256 + kcol;
            float4 v = *(const float4*)(A + gi);
            float4 rv = *(const float4*)(res + gi);
            xs[(cf * 4 + 0) * 36 + rf] = (fmaxf(v.x * scs[kcol + 0] + shs[kcol + 0], 0.f) + rv.x) * INVS;
            xs[(cf * 4 + 1) * 36 + rf] = (fmaxf(v.y * scs[kcol + 1] + shs[kcol + 1], 0.f) + rv.y) * INVS;
            xs[(cf * 4 + 2) * 36 + rf] = (fmaxf(v.z * scs[kcol + 2] + shs[kcol + 2], 0.f) + rv.z) * INVS;
            xs[(cf * 4 + 3) * 36 + rf] = (fmaxf(v.w * scs[kcol + 3] + shs[kcol + 3], 0.f) + rv.w) * INVS;
        }
        {
            int cc = (t & 15) * 4;
            int k = t >> 4;
            #pragma unroll
            for (int pass = 0; pass < 2; pass++, k += 16) {
                *(float4*)(bs + k * 64 + cc) = *(const float4*)(B + (k0 + k) * 64 + cc);
            }
        }
        __syncthreads();
        #pragma unroll 8
        for (int k = 0; k < 32; k++) {
            float2 av = *(const float2*)(xs + k * 36 + r0);
            float4 bv = *(const float4*)(bs + k * 64 + c0);
            acc[0][0] += av.x * bv.x; acc[0][1] += av.x * bv.y;
            acc[0][2] += av.x * bv.z; acc[0][3] += av.x * bv.w;
            acc[1][0] += av.y * bv.x; acc[1][1] += av.y * bv.y;
            acc[1][2] += av.y * bv.z; acc[1][3] += av.y * bv.w;
        }
    }
    float4 bv = *(const float4*)(bias + c0);
    #pragma unroll
    for (int i = 0; i < 2; i++) {
        int gr = row0 + r0 + i;
        float4 o = {acc[i][0] + bv.x, acc[i][1] + bv.y, acc[i][2] + bv.z, acc[i][3] + bv.w};
        *(float4*)(y + gr * 64 + c0) = o;
    }
}

// ---------------- fused mean-pool (sorted batch) + MLP head ----------------

__global__ __launch_bounds__(256) void k_pool_head(const float* __restrict__ x, const int* __restrict__ batch,
                                                   const float* __restrict__ Wh1, const float* __restrict__ bh1,
                                                   const float* __restrict__ Wh2, const float* __restrict__ bh2,
                                                   float* __restrict__ out) {
    const int g = blockIdx.x;
    const int t = threadIdx.x;
    int lo = 0, hi = N_NODES;
    while (lo < hi) { int mid = (lo + hi) >> 1; if (batch[mid] < g) lo = mid + 1; else hi = mid; }
    int start = lo;
    hi = N_NODES;
    while (lo < hi) { int mid = (lo + hi) >> 1; if (batch[mid] < g + 1) lo = mid + 1; else hi = mid; }
    int end = lo;
    float cnt = (float)(end - start);

    __shared__ float part[256];
    __shared__ float p[64];
    __shared__ float hrow[256];
    const int c = t & 63;
    float s = 0.f;
    for (int r = start + (t >> 6); r < end; r += 4) s += x[r * 64 + c];
    part[t] = s;
    __syncthreads();
    if (t < 64) {
        float v = part[t] + part[t + 64] + part[t + 128] + part[t + 192];
        p[t] = v / fmaxf(cnt, 1.f);
    }
    __syncthreads();
    float a = bh1[t];
    #pragma unroll 8
    for (int k = 0; k < 64; k++) a += p[k] * Wh1[k * 256 + t];
    hrow[t] = fmaxf(a, 0.f);
    __syncthreads();
    if (t < 128) {
        float o = bh2[t];
        #pragma unroll 8
        for (int k = 0; k < 256; k++) o += hrow[k] * Wh2[k * 128 + t];
        out[g * 128 + t] = o;
    }
}

// ---------------- host ----------------

extern "C" void kernel_launch(void* const* d_in, const int* in_sizes, int n_in,
                              void* d_out, int out_size, void* d_ws, size_t ws_size,
                              hipStream_t stream) {
    (void)in_sizes; (void)n_in; (void)out_size; (void)ws_size;
    const float* x0 = (const float*)d_in[0];
    const int* ei = (const int*)d_in[1];
    const int* batch = (const int*)d_in[2];
    const float* Wh1 = (const float*)d_in[35];
    const float* bh1 = (const float*)d_in[36];
    const float* Wh2 = (const float*)d_in[37];
    const float* bh2 = (const float*)d_in[38];

    char* p = (char*)d_ws;
    auto alloc = [&](size_t bytes) -> void* {
        void* r = (void*)p;
        p += (bytes + 255) & ~(size_t)255;
        return r;
    };
    // zeroed region: counts + banked BN accumulators + counters (single memset)
    int* counts = (int*)alloc((size_t)N_NODES * 4);
    float* sumR = (float*)alloc(BN_BANKS * 256 * 4);
    float* sumsqR = (float*)alloc(BN_BANKS * 256 * 4);
    int* cntBank = (int*)alloc(BN_BANKS * 16 * 4);  // 64B-strided counters
    int* cntMaster = (int*)alloc(256);
    const size_t zero_bytes = (((size_t)N_NODES * 4 + 255) & ~(size_t)255) + BN_BANKS * 256 * 4 * 2 +
                              BN_BANKS * 16 * 4 + 256;
    int* offs = (int*)alloc((size_t)(N_NODES + 1) * 4);
    int* cursor = (int*)alloc((size_t)N_NODES * 4);
    int* csr_src = (int*)alloc((size_t)ETOT * 4);
    float* alS = (float*)alloc((size_t)N_NODES * 4 * 4);
    float* alD = (float*)alloc((size_t)N_NODES * 4 * 4);
    float* alS2 = (float*)alloc((size_t)N_NODES * 4);
    float* alD2 = (float*)alloc((size_t)N_NODES * 4);
    float* scaleb = (float*)alloc(1024);
    float* shiftb = (float*)alloc(1024);
    unsigned short* hbuf = (unsigned short*)alloc((size_t)N_NODES * 256 * 2);
    float* obuf = (float*)alloc((size_t)N_NODES * 256 * 4);
    float* rbuf = (float*)alloc((size_t)N_NODES * 256 * 4);
    float* xout = (float*)alloc((size_t)N_NODES * 64 * 4);
    unsigned short* Bf2_0 = (unsigned short*)alloc(256 * 256 * 2);
    unsigned short* Bf2_1 = (unsigned short*)alloc(256 * 256 * 2);
    unsigned short* Bf1_0 = (unsigned short*)alloc(64 * 256 * 2);
    unsigned short* Bfr_0 = (unsigned short*)alloc(64 * 256 * 2);
    unsigned short* Bf1_1 = (unsigned short*)alloc(64 * 256 * 2);
    unsigned short* Bfr_1 = (unsigned short*)alloc(64 * 256 * 2);

    hipMemsetAsync(counts, 0, zero_bytes, stream);
    k_hist<<<(ETOT + 255) / 256, 256, 0, stream>>>(ei, counts);
    k_scan<<<1, 1024, 0, stream>>>(counts, offs, cursor);
    k_scatter<<<(ETOT + 255) / 256, 256, 0, stream>>>(ei, cursor, csr_src);
    k_prepB_all<<<96, 256, 0, stream>>>((const float*)d_in[3 + 6], (const float*)d_in[19 + 6],
                                        (const float*)d_in[3 + 0], (const float*)d_in[3 + 12],
                                        (const float*)d_in[19 + 0], (const float*)d_in[19 + 12],
                                        Bf2_0, Bf2_1, Bf1_0, Bfr_0, Bf1_1, Bfr_1);

    const int tile64_blocks = ((N_NODES + 63) / 64) * 4;  // 1252
    const int node_blocks = N_NODES / 4;                  // 5000 (exact; 5000 % 8 == 0)
    const int final_blocks = N_NODES / 32;                // 625

    auto run_block = [&](const float* xin, int base, const unsigned short* Bf2,
                         const unsigned short* Bf1, const unsigned short* Bfr) {
        const float* a1s = (const float*)d_in[base + 1];
        const float* a1d = (const float*)d_in[base + 2];
        const float* b1 = (const float*)d_in[base + 3];
        const float* g1 = (const float*)d_in[base + 4];
        const float* be1 = (const float*)d_in[base + 5];
        const float* a2s = (const float*)d_in[base + 7];
        const float* a2d = (const float*)d_in[base + 8];
        const float* b2 = (const float*)d_in[base + 9];
        const float* g2 = (const float*)d_in[base + 10];
        const float* be2 = (const float*)d_in[base + 11];
        const float* br = (const float*)d_in[base + 13];
        const float* Wf = (const float*)d_in[base + 14];
        const float* bf = (const float*)d_in[base + 15];

        k_gemm64_dual<<<tile64_blocks, 256, 0, stream>>>(xin, Bf1, Bfr, br, a1s, a1d, hbuf, rbuf, alS, alD);
        k_agg_bn<4><<<node_blocks, 256, 0, stream>>>(hbuf, alS, alD, offs, csr_src, b1, obuf,
                                                     sumR, sumsqR, g1, be1, scaleb, shiftb,
                                                     cntBank, cntMaster, alS2, alD2);
        k_gemm256_mfma<<<tile64_blocks, 256, 0, stream>>>(obuf, scaleb, shiftb, Bf2, a2s, a2d, hbuf, alS2, alD2);
        k_agg_bn<1><<<node_blocks, 256, 0, stream>>>(hbuf, alS2, alD2, offs, csr_src, b2, obuf,
                                                     sumR, sumsqR, g2, be2, scaleb, shiftb,
                                                     cntBank, cntMaster, nullptr, nullptr);
        k_gemm_final<<<final_blocks, 256, 0, stream>>>(obuf, scaleb, shiftb, rbuf, Wf, bf, xout);
    };

    run_block(x0, 3, Bf2_0, Bf1_0, Bfr_0);
    run_block(xout, 19, Bf2_1, Bf1_1, Bfr_1);

    k_pool_head<<<G_GROUPS, 256, 0, stream>>>(xout, batch, Wh1, bh1, Wh2, bh2, (float*)d_out);
}

// Round 18
// 589.150 us; speedup vs baseline: 3.8417x; 3.8417x over previous
//
#include <hip/hip_runtime.h>

#define N_NODES 20000
#define N_EDGES 320000
#define ETOT (N_EDGES + N_NODES)
#define G_GROUPS 64
#define BN_BLOCKS 256
#define BN_BANKS 8

typedef __attribute__((ext_vector_type(8))) short bf16x8;
typedef __attribute__((ext_vector_type(4))) float f32x4;

// bf16 helpers (RNE)
__device__ __forceinline__ unsigned short f2bf(float f) {
    unsigned int u = __float_as_uint(f);
    u += 0x7fffu + ((u >> 16) & 1u);
    return (unsigned short)(u >> 16);
}
__device__ __forceinline__ float bf2f(unsigned short v) {
    return __uint_as_float(((unsigned int)v) << 16);
}
__device__ __forceinline__ unsigned int pack2bf(float a, float b) {
    return (unsigned int)f2bf(a) | ((unsigned int)f2bf(b) << 16);
}

// ---------------- CSR build ----------------

__global__ __launch_bounds__(256) void k_hist(const int* __restrict__ ei, int* __restrict__ counts) {
    int e = blockIdx.x * 256 + threadIdx.x;
    if (e >= ETOT) return;
    int dst = (e < N_EDGES) ? ei[N_EDGES + e] : (e - N_EDGES);
    atomicAdd(&counts[dst], 1);
}

__global__ __launch_bounds__(1024) void k_scan(const int* __restrict__ counts, int* __restrict__ offs,
                                               int* __restrict__ cursor) {
    __shared__ int sdata[1024];
    const int t = threadIdx.x;
    const int chunk = (N_NODES + 1023) / 1024;  // 20
    int base = t * chunk;
    int s = 0;
    for (int i = 0; i < chunk; i++) { int idx = base + i; if (idx < N_NODES) s += counts[idx]; }
    sdata[t] = s;
    __syncthreads();
    for (int off = 1; off < 1024; off <<= 1) {
        int v = (t >= off) ? sdata[t - off] : 0;
        __syncthreads();
        sdata[t] += v;
        __syncthreads();
    }
    int prefix = (t == 0) ? 0 : sdata[t - 1];
    for (int i = 0; i < chunk; i++) {
        int idx = base + i;
        if (idx < N_NODES) {
            int cv = counts[idx];
            offs[idx] = prefix;
            cursor[idx] = prefix;
            prefix += cv;
        }
    }
    if (t == 1023) offs[N_NODES] = sdata[1023];
}

__global__ __launch_bounds__(256) void k_scatter(const int* __restrict__ ei, int* __restrict__ cursor,
                                                 int* __restrict__ csr_src) {
    int e = blockIdx.x * 256 + threadIdx.x;
    if (e >= ETOT) return;
    int src = (e < N_EDGES) ? ei[e] : (e - N_EDGES);
    int dst = (e < N_EDGES) ? ei[N_EDGES + e] : (e - N_EDGES);
    int p = atomicAdd(&cursor[dst], 1);
    csr_src[p] = src;
}

// ---------------- pre-pack all weights -> B-fragment-major bf16, ONE dispatch ----------------

__global__ __launch_bounds__(256) void k_prepB_all(const float* __restrict__ W2a, const float* __restrict__ W2b,
                                                   const float* __restrict__ W1a, const float* __restrict__ Wra,
                                                   const float* __restrict__ W1b, const float* __restrict__ Wrb,
                                                   unsigned short* __restrict__ B2a, unsigned short* __restrict__ B2b,
                                                   unsigned short* __restrict__ B1a, unsigned short* __restrict__ Bra,
                                                   unsigned short* __restrict__ B1b, unsigned short* __restrict__ Brb) {
    int b = blockIdx.x;
    const float* W;
    unsigned short* Bf;
    int s0;
    if (b < 32) { W = W2a; Bf = B2a; s0 = b; }
    else if (b < 64) { W = W2b; Bf = B2b; s0 = b - 32; }
    else if (b < 72) { W = W1a; Bf = B1a; s0 = b - 64; }
    else if (b < 80) { W = Wra; Bf = Bra; s0 = b - 72; }
    else if (b < 88) { W = W1b; Bf = B1b; s0 = b - 80; }
    else { W = Wrb; Bf = Brb; s0 = b - 88; }
    int s = s0 * 256 + threadIdx.x;
    int l = s & 63;
    int nt = (s >> 6) & 15;
    int kt = s >> 10;
    int n = nt * 16 + (l & 15);
    int kb = kt * 32 + (l >> 4) * 8;
    float v[8];
    #pragma unroll
    for (int j = 0; j < 8; j++) v[j] = W[(kb + j) * 256 + n];
    uint4 q = {pack2bf(v[0], v[1]), pack2bf(v[2], v[3]), pack2bf(v[4], v[5]), pack2bf(v[6], v[7])};
    *(uint4*)(Bf + s * 8) = q;
}

// ---------------- MFMA dual GEMM [N,64]x[64,256] (W1 & Wr), alpha fused ----------------

__global__ __launch_bounds__(256) void k_gemm64_dual(const float* __restrict__ x,
                                                     const unsigned short* __restrict__ Bf1,
                                                     const unsigned short* __restrict__ Bfr,
                                                     const float* __restrict__ br,
                                                     const float* __restrict__ a_s, const float* __restrict__ a_d,
                                                     unsigned short* __restrict__ hbf, float* __restrict__ res,
                                                     float* __restrict__ alS, float* __restrict__ alD) {
    const int rb = blockIdx.x >> 2, cs = blockIdx.x & 3;
    const int row0 = rb * 64;
    const int nrows = min(64, N_NODES - row0);
    const int t = threadIdx.x;
    const int w = t >> 6;
    const int l = t & 63;
    const int quad = l >> 4;
    const int colLocal = l & 15;
    __shared__ unsigned short As[8 * 64 * 8];  // 8 KB
    __shared__ float alsm[4][64], aldm[4][64];

    const int ntg = cs * 4 + w;
    bf16x8 b1f[2], brf[2];
    #pragma unroll
    for (int kt = 0; kt < 2; kt++) {
        b1f[kt] = *(const bf16x8*)(Bf1 + ((kt * 16 + ntg) * 64 + l) * 8);
        brf[kt] = *(const bf16x8*)(Bfr + ((kt * 16 + ntg) * 64 + l) * 8);
    }

    #pragma unroll
    for (int gi = 0; gi < 2; gi++) {
        int g = 2 * w + gi;
        int kt = g >> 2, mt = g & 3;
        int sm = mt * 16 + (l & 15);
        int koff = kt * 32 + (l >> 4) * 8;
        float4 v0 = {0.f, 0.f, 0.f, 0.f}, v1 = {0.f, 0.f, 0.f, 0.f};
        if (sm < nrows) {
            v0 = *(const float4*)(x + (row0 + sm) * 64 + koff);
            v1 = *(const float4*)(x + (row0 + sm) * 64 + koff + 4);
        }
        uint4 q = {pack2bf(v0.x, v0.y), pack2bf(v0.z, v0.w), pack2bf(v1.x, v1.y), pack2bf(v1.z, v1.w)};
        *(uint4*)(As + (g * 64 + l) * 8) = q;
    }
    __syncthreads();

    f32x4 acc1[4], acc2[4];
    #pragma unroll
    for (int mt = 0; mt < 4; mt++) {
        acc1[mt] = (f32x4){0.f, 0.f, 0.f, 0.f};
        acc2[mt] = (f32x4){0.f, 0.f, 0.f, 0.f};
    }
    #pragma unroll
    for (int kt = 0; kt < 2; kt++) {
        #pragma unroll
        for (int mt = 0; mt < 4; mt++) {
            bf16x8 af = *(const bf16x8*)(As + ((kt * 4 + mt) * 64 + l) * 8);
            acc1[mt] = __builtin_amdgcn_mfma_f32_16x16x32_bf16(af, b1f[kt], acc1[mt], 0, 0, 0);
            acc2[mt] = __builtin_amdgcn_mfma_f32_16x16x32_bf16(af, brf[kt], acc2[mt], 0, 0, 0);
        }
    }

    const int col = cs * 64 + w * 16 + colLocal;
    const float brv = br[col];
    const float asv = a_s[col];
    const float adv = a_d[col];
    #pragma unroll
    for (int mt = 0; mt < 4; mt++) {
        #pragma unroll
        for (int r = 0; r < 4; r++) {
            float v1 = acc1[mt][r];
            int lr = mt * 16 + quad * 4 + r;
            bool ok = lr < nrows;
            int row = row0 + lr;
            if (ok) {
                hbf[row * 256 + col] = f2bf(v1);
                res[row * 256 + col] = acc2[mt][r] + brv;
            }
            float ps = v1 * asv, pd = v1 * adv;
            #pragma unroll
            for (int off = 1; off < 16; off <<= 1) {
                ps += __shfl_xor(ps, off);
                pd += __shfl_xor(pd, off);
            }
            if (colLocal == 0) {
                alsm[w][lr] = ps;
                aldm[w][lr] = pd;
            }
        }
    }
    __syncthreads();
    if (t < 64 && t < nrows) {
        float s = (alsm[0][t] + alsm[1][t]) + (alsm[2][t] + alsm[3][t]);
        float d = (aldm[0][t] + aldm[1][t]) + (aldm[2][t] + aldm[3][t]);
        alS[(row0 + t) * 4 + cs] = s;
        alD[(row0 + t) * 4 + cs] = d;
    }
}

// ---------------- CSR softmax-aggregation, scalar index/logit loads, 16-deep gather pipeline ----------------

template <int H>
__global__ __launch_bounds__(256) void k_agg(const unsigned short* __restrict__ hbf, const float* __restrict__ alS,
                                             const float* __restrict__ alD, const int* __restrict__ offs,
                                             const int* __restrict__ csr_src, const float* __restrict__ bias,
                                             float* __restrict__ out) {
    const int node = __builtin_amdgcn_readfirstlane(blockIdx.x * 4 + (threadIdx.x >> 6));  // grid exact: 5000*4
    const int lane = threadIdx.x & 63;
    const int head = (H == 4) ? (lane >> 4) : 0;
    float ald;
    if (H == 4) {
        float4 d4 = *(const float4*)(alD + node * 4);
        ald = (head == 0) ? d4.x : (head == 1) ? d4.y : (head == 2) ? d4.z : d4.w;
    } else {
        ald = alD[node];
    }
    const int e0 = offs[node], e1 = offs[node + 1];
    const unsigned short* hp = hbf + lane * 4;
    float den = 0.f, a0 = 0.f, a1 = 0.f, a2 = 0.f, a3 = 0.f;
    int e = e0;
    for (; e + 16 <= e1; e += 16) {
        int s[16];
        #pragma unroll
        for (int i = 0; i < 16; i++) s[i] = csr_src[e + i];  // s_load (uniform)
        ushort4 hq[16];
        #pragma unroll
        for (int i = 0; i < 16; i++) hq[i] = *(const ushort4*)(hp + s[i] * 256);  // 16 gathers in flight
        float w[16];
        #pragma unroll
        for (int i = 0; i < 16; i++) {
            float v;
            if (H == 4) {
                float4 s4 = *(const float4*)(alS + s[i] * 4);
                float as = (head == 0) ? s4.x : (head == 1) ? s4.y : (head == 2) ? s4.z : s4.w;
                v = as + ald;
            } else {
                v = alS[s[i]] + ald;
            }
            v = (v > 0.f) ? v : 0.2f * v;
            w[i] = __expf(v);
        }
        #pragma unroll
        for (int i = 0; i < 16; i++) {
            den += w[i];
            a0 += w[i] * bf2f(hq[i].x); a1 += w[i] * bf2f(hq[i].y);
            a2 += w[i] * bf2f(hq[i].z); a3 += w[i] * bf2f(hq[i].w);
        }
    }
    for (; e < e1; e++) {
        int s = csr_src[e];
        float v;
        if (H == 4) {
            float4 s4 = *(const float4*)(alS + s * 4);
            float as = (head == 0) ? s4.x : (head == 1) ? s4.y : (head == 2) ? s4.z : s4.w;
            v = as + ald;
        } else {
            v = alS[s] + ald;
        }
        v = (v > 0.f) ? v : 0.2f * v;
        float w = __expf(v);
        ushort4 hq = *(const ushort4*)(hp + s * 256);
        den += w;
        a0 += w * bf2f(hq.x); a1 += w * bf2f(hq.y); a2 += w * bf2f(hq.z); a3 += w * bf2f(hq.w);
    }
    float inv = 1.f / den;
    const float4 bv = *(const float4*)(bias + lane * 4);
    float4 o = {a0 * inv + bv.x, a1 * inv + bv.y, a2 * inv + bv.z, a3 * inv + bv.w};
    *(float4*)(out + node * 256 + lane * 4) = o;
}

// ---------------- BatchNorm: stats + finalize, 8-way banked atomics (contention /8) ----------------

__global__ __launch_bounds__(256) void k_bnstats_fin(const float* __restrict__ x, float* __restrict__ sumR,
                                                     float* __restrict__ sumsqR, const float* __restrict__ g,
                                                     const float* __restrict__ be, float* __restrict__ scale,
                                                     float* __restrict__ shift, int* __restrict__ counter,
                                                     float* __restrict__ zS, float* __restrict__ zD) {
    const int c = threadIdx.x;
    const int bank = blockIdx.x & (BN_BANKS - 1);
    if (zS) {  // zero next-stage alpha accumulators (256 blocks x 256 threads covers N_NODES)
        int idx = blockIdx.x * 256 + c;
        if (idx < N_NODES) { zS[idx] = 0.f; zD[idx] = 0.f; }
    }
    float s = 0.f, q = 0.f;
    int r = blockIdx.x;
    for (; r + 3 * BN_BLOCKS < N_NODES; r += 4 * BN_BLOCKS) {
        float v0 = x[r * 256 + c];
        float v1 = x[(r + BN_BLOCKS) * 256 + c];
        float v2 = x[(r + 2 * BN_BLOCKS) * 256 + c];
        float v3 = x[(r + 3 * BN_BLOCKS) * 256 + c];
        s += (v0 + v1) + (v2 + v3);
        q += (v0 * v0 + v1 * v1) + (v2 * v2 + v3 * v3);
    }
    for (; r < N_NODES; r += BN_BLOCKS) {
        float v = x[r * 256 + c];
        s += v; q += v * v;
    }
    atomicAdd(&sumR[bank * 256 + c], s);
    atomicAdd(&sumsqR[bank * 256 + c], q);
    __threadfence();
    __syncthreads();
    __shared__ int lastFlag;
    if (c == 0) lastFlag = (atomicAdd(counter, 1) == (int)gridDim.x - 1);
    __syncthreads();
    if (lastFlag) {
        float S = 0.f, Q = 0.f;
        #pragma unroll
        for (int k = 0; k < BN_BANKS; k++) {
            S += atomicAdd(&sumR[k * 256 + c], 0.f);    // coherent read
            Q += atomicAdd(&sumsqR[k * 256 + c], 0.f);
        }
        float mu = S * (1.f / N_NODES);
        float var = Q * (1.f / N_NODES) - mu * mu;
        float sc = g[c] * rsqrtf(var + 1e-5f);
        scale[c] = sc;
        shift[c] = be[c] - mu * sc;
        #pragma unroll
        for (int k = 0; k < BN_BANKS; k++) {  // re-zero for next BN (visible at kernel boundary)
            sumR[k * 256 + c] = 0.f;
            sumsqR[k * 256 + c] = 0.f;
        }
        if (c == 0) *counter = 0;
    }
}

// ---------------- MFMA GEMM: bf16(relu(bn(A))) @ bf16(W2), alpha via atomics ----------------

__global__ __launch_bounds__(256) void k_gemm256_mfma(const float* __restrict__ A, const float* __restrict__ scale,
                                                      const float* __restrict__ shift,
                                                      const unsigned short* __restrict__ Bf,
                                                      const float* __restrict__ a_s, const float* __restrict__ a_d,
                                                      unsigned short* __restrict__ C, float* __restrict__ alS2,
                                                      float* __restrict__ alD2) {
    const int rb = blockIdx.x >> 2, cs = blockIdx.x & 3;
    const int row0 = rb * 64;
    const int nrows = min(64, N_NODES - row0);
    const int t = threadIdx.x;
    const int w = t >> 6;
    const int l = t & 63;
    const int quad = l >> 4;
    const int colLocal = l & 15;
    __shared__ unsigned short As[2 * 4 * 64 * 8];  // 8 KB
    __shared__ float scs[256], shs[256];
    scs[t] = scale[t];
    shs[t] = shift[t];

    const int ntg = cs * 4 + w;
    bf16x8 bfrag[8];
    #pragma unroll
    for (int kt = 0; kt < 8; kt++)
        bfrag[kt] = *(const bf16x8*)(Bf + ((kt * 16 + ntg) * 64 + l) * 8);

    f32x4 acc[4];
    #pragma unroll
    for (int mt = 0; mt < 4; mt++) acc[mt] = (f32x4){0.f, 0.f, 0.f, 0.f};

    const int smt = (t >> 6) & 3;
    const int sm = smt * 16 + (l & 15);
    const int skoff = (l >> 4) * 8;

    for (int kc = 0; kc < 4; kc++) {
        __syncthreads();
        #pragma unroll
        for (int kt2 = 0; kt2 < 2; kt2++) {
            int k = kc * 64 + kt2 * 32 + skoff;
            float4 v0 = {0.f, 0.f, 0.f, 0.f}, v1 = {0.f, 0.f, 0.f, 0.f};
            if (sm < nrows) {
                v0 = *(const float4*)(A + (row0 + sm) * 256 + k);
                v1 = *(const float4*)(A + (row0 + sm) * 256 + k + 4);
                v0.x = fmaxf(v0.x * scs[k + 0] + shs[k + 0], 0.f);
                v0.y = fmaxf(v0.y * scs[k + 1] + shs[k + 1], 0.f);
                v0.z = fmaxf(v0.z * scs[k + 2] + shs[k + 2], 0.f);
                v0.w = fmaxf(v0.w * scs[k + 3] + shs[k + 3], 0.f);
                v1.x = fmaxf(v1.x * scs[k + 4] + shs[k + 4], 0.f);
                v1.y = fmaxf(v1.y * scs[k + 5] + shs[k + 5], 0.f);
                v1.z = fmaxf(v1.z * scs[k + 6] + shs[k + 6], 0.f);
                v1.w = fmaxf(v1.w * scs[k + 7] + shs[k + 7], 0.f);
            }
            uint4 q = {pack2bf(v0.x, v0.y), pack2bf(v0.z, v0.w), pack2bf(v1.x, v1.y), pack2bf(v1.z, v1.w)};
            *(uint4*)(As + ((kt2 * 4 + smt) * 64 + l) * 8) = q;
        }
        __syncthreads();
        #pragma unroll
        for (int kt2 = 0; kt2 < 2; kt2++) {
            int ktg = kc * 2 + kt2;
            #pragma unroll
            for (int mt = 0; mt < 4; mt++) {
                bf16x8 af = *(const bf16x8*)(As + ((kt2 * 4 + mt) * 64 + l) * 8);
                acc[mt] = __builtin_amdgcn_mfma_f32_16x16x32_bf16(af, bfrag[ktg], acc[mt], 0, 0, 0);
            }
        }
    }

    const int col = cs * 64 + w * 16 + colLocal;
    const float asv = a_s[col];
    const float adv = a_d[col];
    #pragma unroll
    for (int mt = 0; mt < 4; mt++) {
        #pragma unroll
        for (int r = 0; r < 4; r++) {
            float v = acc[mt][r];
            int lr = mt * 16 + quad * 4 + r;
            bool ok = lr < nrows;
            int row = row0 + lr;
            if (ok) C[row * 256 + col] = f2bf(v);
            float ps = v * asv, pd = v * adv;
            #pragma unroll
            for (int off = 1; off < 16; off <<= 1) {
                ps += __shfl_xor(ps, off);
                pd += __shfl_xor(pd, off);
            }
            if (colLocal == 0 && ok) {
                atomicAdd(&alS2[row], ps);
                atomicAdd(&alD2[row], pd);
            }
        }
    }
}

// ---------------- final GEMM ((relu(bn(A))+res)*invsqrt2)@Wf+bf -> [N,64], 32x64 tiles ----------------

__global__ __launch_bounds__(256) void k_gemm_final(const float* __restrict__ A, const float* __restrict__ scale,
                                                    const float* __restrict__ shift, const float* __restrict__ res,
                                                    const float* __restrict__ B, const float* __restrict__ bias,
                                                    float* __restrict__ y) {
    const int row0 = blockIdx.x * 32;
    const int t = threadIdx.x;
    const float INVS = 0.70710678118654752440f;
    __shared__ float xs[32 * 36];
    __shared__ float bs[32 * 64];
    __shared__ float scs[256], shs[256];
    scs[t] = scale[t];
    shs[t] = shift[t];
    const int rf = (t & 15) | ((t >> 7) << 4);
    const int cf = (t >> 4) & 7;
    const int c0 = (t & 15) * 4;
    const int r0 = (t >> 4) * 2;
    float acc[2][4] = {};
    for (int k0 = 0; k0 < 256; k0 += 32) {
        __syncthreads();
        {
            int kcol = k0 + cf * 4;
            int gi = (row0 + rf) * 256 + kcol;
            float4 v = *(const float4*)(A + gi);
            float4 rv = *(const float4*)(res + gi);
            xs[(cf * 4 + 0) * 36 + rf] = (fmaxf(v.x * scs[kcol + 0] + shs[kcol + 0], 0.f) + rv.x) * INVS;
            xs[(cf * 4 + 1) * 36 + rf] = (fmaxf(v.y * scs[kcol + 1] + shs[kcol + 1], 0.f) + rv.y) * INVS;
            xs[(cf * 4 + 2) * 36 + rf] = (fmaxf(v.z * scs[kcol + 2] + shs[kcol + 2], 0.f) + rv.z) * INVS;
            xs[(cf * 4 + 3) * 36 + rf] = (fmaxf(v.w * scs[kcol + 3] + shs[kcol + 3], 0.f) + rv.w) * INVS;
        }
        {
            int cc = (t & 15) * 4;
            int k = t >> 4;
            #pragma unroll
            for (int pass = 0; pass < 2; pass++, k += 16) {
                *(float4*)(bs + k * 64 + cc) = *(const float4*)(B + (k0 + k) * 64 + cc);
            }
        }
        __syncthreads();
        #pragma unroll 8
        for (int k = 0; k < 32; k++) {
            float2 av = *(const float2*)(xs + k * 36 + r0);
            float4 bv = *(const float4*)(bs + k * 64 + c0);
            acc[0][0] += av.x * bv.x; acc[0][1] += av.x * bv.y;
            acc[0][2] += av.x * bv.z; acc[0][3] += av.x * bv.w;
            acc[1][0] += av.y * bv.x; acc[1][1] += av.y * bv.y;
            acc[1][2] += av.y * bv.z; acc[1][3] += av.y * bv.w;
        }
    }
    float4 bv = *(const float4*)(bias + c0);
    #pragma unroll
    for (int i = 0; i < 2; i++) {
        int gr = row0 + r0 + i;
        float4 o = {acc[i][0] + bv.x, acc[i][1] + bv.y, acc[i][2] + bv.z, acc[i][3] + bv.w};
        *(float4*)(y + gr * 64 + c0) = o;
    }
}

// ---------------- fused mean-pool (sorted batch) + MLP head ----------------

__global__ __launch_bounds__(256) void k_pool_head(const float* __restrict__ x, const int* __restrict__ batch,
                                                   const float* __restrict__ Wh1, const float* __restrict__ bh1,
                                                   const float* __restrict__ Wh2, const float* __restrict__ bh2,
                                                   float* __restrict__ out) {
    const int g = blockIdx.x;
    const int t = threadIdx.x;
    int lo = 0, hi = N_NODES;
    while (lo < hi) { int mid = (lo + hi) >> 1; if (batch[mid] < g) lo = mid + 1; else hi = mid; }
    int start = lo;
    hi = N_NODES;
    while (lo < hi) { int mid = (lo + hi) >> 1; if (batch[mid] < g + 1) lo = mid + 1; else hi = mid; }
    int end = lo;
    float cnt = (float)(end - start);

    __shared__ float part[256];
    __shared__ float p[64];
    __shared__ float hrow[256];
    const int c = t & 63;
    float s = 0.f;
    for (int r = start + (t >> 6); r < end; r += 4) s += x[r * 64 + c];
    part[t] = s;
    __syncthreads();
    if (t < 64) {
        float v = part[t] + part[t + 64] + part[t + 128] + part[t + 192];
        p[t] = v / fmaxf(cnt, 1.f);
    }
    __syncthreads();
    float a = bh1[t];
    #pragma unroll 8
    for (int k = 0; k < 64; k++) a += p[k] * Wh1[k * 256 + t];
    hrow[t] = fmaxf(a, 0.f);
    __syncthreads();
    if (t < 128) {
        float o = bh2[t];
        #pragma unroll 8
        for (int k = 0; k < 256; k++) o += hrow[k] * Wh2[k * 128 + t];
        out[g * 128 + t] = o;
    }
}

// ---------------- host ----------------

extern "C" void kernel_launch(void* const* d_in, const int* in_sizes, int n_in,
                              void* d_out, int out_size, void* d_ws, size_t ws_size,
                              hipStream_t stream) {
    (void)in_sizes; (void)n_in; (void)out_size; (void)ws_size;
    const float* x0 = (const float*)d_in[0];
    const int* ei = (const int*)d_in[1];
    const int* batch = (const int*)d_in[2];
    const float* Wh1 = (const float*)d_in[35];
    const float* bh1 = (const float*)d_in[36];
    const float* Wh2 = (const float*)d_in[37];
    const float* bh2 = (const float*)d_in[38];

    char* p = (char*)d_ws;
    auto alloc = [&](size_t bytes) -> void* {
        void* r = (void*)p;
        p += (bytes + 255) & ~(size_t)255;
        return r;
    };
    // zeroed region: counts + banked BN accumulators + counter (single memset)
    int* counts = (int*)alloc((size_t)N_NODES * 4);          // padded to 80128
    float* sumR = (float*)alloc(BN_BANKS * 256 * 4);         // 8 KB
    float* sumsqR = (float*)alloc(BN_BANKS * 256 * 4);       // 8 KB
    int* bncnt = (int*)alloc(256);
    const size_t zero_bytes = (((size_t)N_NODES * 4 + 255) & ~(size_t)255) + BN_BANKS * 256 * 4 * 2 + 256;
    int* offs = (int*)alloc((size_t)(N_NODES + 1) * 4);
    int* cursor = (int*)alloc((size_t)N_NODES * 4);
    int* csr_src = (int*)alloc((size_t)ETOT * 4);
    float* alS = (float*)alloc((size_t)N_NODES * 4 * 4);
    float* alD = (float*)alloc((size_t)N_NODES * 4 * 4);
    float* alS2 = (float*)alloc((size_t)N_NODES * 4);
    float* alD2 = (float*)alloc((size_t)N_NODES * 4);
    float* scaleb = (float*)alloc(1024);
    float* shiftb = (float*)alloc(1024);
    unsigned short* hbuf = (unsigned short*)alloc((size_t)N_NODES * 256 * 2);
    float* obuf = (float*)alloc((size_t)N_NODES * 256 * 4);
    float* rbuf = (float*)alloc((size_t)N_NODES * 256 * 4);
    float* xout = (float*)alloc((size_t)N_NODES * 64 * 4);
    unsigned short* Bf2_0 = (unsigned short*)alloc(256 * 256 * 2);
    unsigned short* Bf2_1 = (unsigned short*)alloc(256 * 256 * 2);
    unsigned short* Bf1_0 = (unsigned short*)alloc(64 * 256 * 2);
    unsigned short* Bfr_0 = (unsigned short*)alloc(64 * 256 * 2);
    unsigned short* Bf1_1 = (unsigned short*)alloc(64 * 256 * 2);
    unsigned short* Bfr_1 = (unsigned short*)alloc(64 * 256 * 2);

    hipMemsetAsync(counts, 0, zero_bytes, stream);
    k_hist<<<(ETOT + 255) / 256, 256, 0, stream>>>(ei, counts);
    k_scan<<<1, 1024, 0, stream>>>(counts, offs, cursor);
    k_scatter<<<(ETOT + 255) / 256, 256, 0, stream>>>(ei, cursor, csr_src);
    k_prepB_all<<<96, 256, 0, stream>>>((const float*)d_in[3 + 6], (const float*)d_in[19 + 6],
                                        (const float*)d_in[3 + 0], (const float*)d_in[3 + 12],
                                        (const float*)d_in[19 + 0], (const float*)d_in[19 + 12],
                                        Bf2_0, Bf2_1, Bf1_0, Bfr_0, Bf1_1, Bfr_1);

    const int tile64_blocks = ((N_NODES + 63) / 64) * 4;  // 1252
    const int node_blocks = N_NODES / 4;                  // 5000 (exact)
    const int final_blocks = N_NODES / 32;                // 625

    auto run_block = [&](const float* xin, int base, const unsigned short* Bf2,
                         const unsigned short* Bf1, const unsigned short* Bfr) {
        const float* a1s = (const float*)d_in[base + 1];
        const float* a1d = (const float*)d_in[base + 2];
        const float* b1 = (const float*)d_in[base + 3];
        const float* g1 = (const float*)d_in[base + 4];
        const float* be1 = (const float*)d_in[base + 5];
        const float* a2s = (const float*)d_in[base + 7];
        const float* a2d = (const float*)d_in[base + 8];
        const float* b2 = (const float*)d_in[base + 9];
        const float* g2 = (const float*)d_in[base + 10];
        const float* be2 = (const float*)d_in[base + 11];
        const float* br = (const float*)d_in[base + 13];
        const float* Wf = (const float*)d_in[base + 14];
        const float* bf = (const float*)d_in[base + 15];

        k_gemm64_dual<<<tile64_blocks, 256, 0, stream>>>(xin, Bf1, Bfr, br, a1s, a1d, hbuf, rbuf, alS, alD);
        k_agg<4><<<node_blocks, 256, 0, stream>>>(hbuf, alS, alD, offs, csr_src, b1, obuf);
        k_bnstats_fin<<<BN_BLOCKS, 256, 0, stream>>>(obuf, sumR, sumsqR, g1, be1, scaleb, shiftb, bncnt, alS2, alD2);
        k_gemm256_mfma<<<tile64_blocks, 256, 0, stream>>>(obuf, scaleb, shiftb, Bf2, a2s, a2d, hbuf, alS2, alD2);
        k_agg<1><<<node_blocks, 256, 0, stream>>>(hbuf, alS2, alD2, offs, csr_src, b2, obuf);
        k_bnstats_fin<<<BN_BLOCKS, 256, 0, stream>>>(obuf, sumR, sumsqR, g2, be2, scaleb, shiftb, bncnt, nullptr, nullptr);
        k_gemm_final<<<final_blocks, 256, 0, stream>>>(obuf, scaleb, shiftb, rbuf, Wf, bf, xout);
    };

    run_block(x0, 3, Bf2_0, Bf1_0, Bfr_0);
    run_block(xout, 19, Bf2_1, Bf1_1, Bfr_1);

    k_pool_head<<<G_GROUPS, 256, 0, stream>>>(xout, batch, Wh1, bh1, Wh2, bh2, (float*)d_out);
}